// Round 1
// baseline (1491.256 us; speedup 1.0000x reference)
//
#include <hip/hip_runtime.h>
#include <cstdint>
#include <cstddef>

// Problem constants (fixed by the reference).
constexpr int Bn = 2048, Ln = 128, Cn = 32, Hn = 64, On = 16;
constexpr int NIv = Ln - 1;                       // 127 intervals
constexpr float K2 = 2.885390081777927f;          // 2*log2(e): tanh(x)=1-2/(1+exp2(K2*x))

__device__ __forceinline__ float fexp2(float x) {
#if __has_builtin(__builtin_amdgcn_exp2f)
  return __builtin_amdgcn_exp2f(x);
#else
  float r; asm("v_exp_f32 %0, %1" : "=v"(r) : "v"(x)); return r;
#endif
}
__device__ __forceinline__ float frcpf(float x) {
#if __has_builtin(__builtin_amdgcn_rcpf)
  return __builtin_amdgcn_rcpf(x);
#else
  float r; asm("v_rcp_f32 %0, %1" : "=v"(r) : "v"(x)); return r;
#endif
}
__device__ __forceinline__ float tanh_fast(float x) {
  float e = fexp2(K2 * x);
  return fmaf(-2.0f, frcpf(e + 1.0f), 1.0f);
}

// ---------------------------------------------------------------------------
// Kernel 1: the sequential RK4 scan. One wave64 per batch element; lane = h.
// Writes tanh(z_l) for l=0..127 into zt (B, L, H) in d_ws.
// W2/b2 pre-scaled by K2 live in VGPRs (96 regs); dXdt vectors in per-wave LDS.
// No __syncthreads needed: waves are fully independent (per-wave LDS slots).
// ---------------------------------------------------------------------------
__global__ __launch_bounds__(256, 2) void ncde_scan_kernel(
    const float* __restrict__ coeffs, const float* __restrict__ t,
    const float* __restrict__ W_init, const float* __restrict__ b_init,
    const float* __restrict__ W1, const float* __restrict__ b1,
    const float* __restrict__ W2, const float* __restrict__ b2,
    float* __restrict__ zt)
{
  __shared__ float sdx[4][5][32];     // [wave][s-index][c]
  const int wv = threadIdx.x >> 6;
  const int lane = threadIdx.x & 63;
  const int b = (blockIdx.x << 2) | wv;

  // Per-lane weights. W1 (H,2); W2 (2, H*C); lane h owns W2[:, h*32 .. h*32+31].
  const float w10 = W1[2 * lane], w11 = W1[2 * lane + 1];
  const float sb0 = b1[0], sb1 = b1[1];
  float w20[32], w21[32], bb[32];
  {
    const float* W2a = W2 + lane * 32;
    const float* W2b = W2 + 2048 + lane * 32;
    const float* b2a = b2 + lane * 32;
#pragma unroll
    for (int c4 = 0; c4 < 8; ++c4) {
      float4 x0 = *(const float4*)(W2a + 4 * c4);
      float4 x1 = *(const float4*)(W2b + 4 * c4);
      float4 x2 = *(const float4*)(b2a + 4 * c4);
      w20[4*c4+0] = x0.x*K2; w20[4*c4+1] = x0.y*K2; w20[4*c4+2] = x0.z*K2; w20[4*c4+3] = x0.w*K2;
      w21[4*c4+0] = x1.x*K2; w21[4*c4+1] = x1.y*K2; w21[4*c4+2] = x1.z*K2; w21[4*c4+3] = x1.w*K2;
      bb [4*c4+0] = x2.x*K2; bb [4*c4+1] = x2.y*K2; bb [4*c4+2] = x2.z*K2; bb [4*c4+3] = x2.w*K2;
    }
  }

  // z0 = X0 @ W_init + b_init, X0 = a-part of interval 0.
  const float* cb0 = coeffs + (size_t)b * NIv * 128;
  if (lane < 32) sdx[wv][0][lane] = cb0[lane];
  __builtin_amdgcn_wave_barrier();
  float z = b_init[lane];
#pragma unroll 4
  for (int c = 0; c < 32; ++c)
    z = fmaf(sdx[wv][0][c], W_init[(c << 6) + lane], z);
  zt[(size_t)b * Ln * Hn + lane] = tanh_fast(z);

  for (int i = 0; i < NIv; ++i) {
    const float* cb = cb0 + (size_t)i * 128;
    const float dti = t[i + 1] - t[i];
    const float hst = 0.5f * dti;
    // Precompute the 5 distinct dXdt vectors (s = 0, .25, .5, .75, 1 times dti).
    __builtin_amdgcn_wave_barrier();
    if (lane < 32) {
      const float bi = cb[32 + lane];
      const float ci = cb[64 + lane];
      const float di = cb[96 + lane];
      const float q = 0.25f * dti;
#pragma unroll
      for (int k = 0; k < 5; ++k) {
        const float s = q * (float)k;
        sdx[wv][k][lane] = fmaf(fmaf(di, s, ci), s, bi);
      }
    }
    __builtin_amdgcn_wave_barrier();

#pragma unroll 1
    for (int j = 0; j < 2; ++j) {          // N_SUB substeps
      float kacc = 0.0f, kprev = 0.0f;
#pragma unroll
      for (int st = 0; st < 4; ++st) {     // RK4 stages
        const float cin = (st == 0) ? 0.0f : (st == 3) ? hst : 0.5f * hst;
        const float wgt = (st == 1 || st == 2) ? 2.0f : 1.0f;
        const float* dx = &sdx[wv][2 * j + ((st + 1) >> 1)][0];
        const float zs = fmaf(cin, kprev, z);
        // h1 = relu(zs @ W1 + b1): two interleaved 64-lane butterflies.
        float p0 = zs * w10, p1 = zs * w11;
#pragma unroll
        for (int m = 1; m < 64; m <<= 1) {
          p0 += __shfl_xor(p0, m, 64);
          p1 += __shfl_xor(p1, m, 64);
        }
        const float h10 = fmaxf(p0 + sb0, 0.0f);
        const float h11 = fmaxf(p1 + sb1, 0.0f);
        float acc = 0.0f;
#pragma unroll
        for (int c4 = 0; c4 < 8; ++c4) {
          const float4 d4 = *(const float4*)(dx + 4 * c4);
          const float dv0 = d4.x, dv1 = d4.y, dv2 = d4.z, dv3 = d4.w;
#pragma unroll
          for (int q2 = 0; q2 < 4; ++q2) {
            const int c = 4 * c4 + q2;
            const float u = fmaf(h10, w20[c], fmaf(h11, w21[c], bb[c]));
            const float e = fexp2(u);
            const float r = frcpf(e + 1.0f);
            const float th = fmaf(-2.0f, r, 1.0f);
            const float dvq = (q2 == 0) ? dv0 : (q2 == 1) ? dv1 : (q2 == 2) ? dv2 : dv3;
            acc = fmaf(th, dvq, acc);
          }
        }
        kprev = acc;
        kacc = fmaf(wgt, acc, kacc);
      }
      z = fmaf(hst * (1.0f / 6.0f), kacc, z);
    }
    zt[((size_t)b * Ln + (i + 1)) * Hn + lane] = tanh_fast(z);
  }
}

// ---------------------------------------------------------------------------
// Kernel 2: readout + hermite coeffs. One block per batch element.
// pred[l][o] = tanh(z)[l] @ W_read + b_read; then cubic-hermite packing.
// LDS index swizzles kill the stride-64 / stride-16 bank conflicts.
// ---------------------------------------------------------------------------
#define SPX(l_, o_) (((l_) << 4) | (((o_) + (l_)) & 15))
#define SZX(l_, h_) (((l_) << 6) | (((h_) + (l_)) & 63))

__global__ __launch_bounds__(128, 2) void ncde_epilogue_kernel(
    const float* __restrict__ zt, const float* __restrict__ t,
    const float* __restrict__ W_read, const float* __restrict__ b_read,
    float* __restrict__ out)
{
  __shared__ float sW[Hn * On];
  __shared__ float sz[Ln * Hn];
  __shared__ float sp[Ln * On];
  __shared__ float st_[Ln];
  const int b = blockIdx.x;
  const int tid = threadIdx.x;

  for (int i2 = tid; i2 < Hn * On; i2 += 128) sW[i2] = W_read[i2];
  st_[tid] = t[tid];
  const float* zb = zt + (size_t)b * Ln * Hn;
#pragma unroll 1
  for (int r = 0; r < 16; ++r) {
    const int base = (r * 128 + tid) * 4;       // 8192 floats, float4-granular
    const float4 v = *(const float4*)(zb + base);
    const int l = base >> 6, h = base & 63;     // h multiple of 4, no row wrap
    sz[SZX(l, h + 0)] = v.x;
    sz[SZX(l, h + 1)] = v.y;
    sz[SZX(l, h + 2)] = v.z;
    sz[SZX(l, h + 3)] = v.w;
  }
  __syncthreads();

  // Readout: thread tid owns row l = tid, all 16 outputs in registers.
  float acc0[On];
#pragma unroll
  for (int o = 0; o < On; ++o) acc0[o] = b_read[o];
#pragma unroll 2
  for (int h = 0; h < Hn; ++h) {
    const float zv = sz[SZX(tid, h)];
#pragma unroll
    for (int o = 0; o < On; ++o) acc0[o] = fmaf(zv, sW[h * On + o], acc0[o]);
  }
  float* po = out + ((size_t)b * Ln + tid) * On;
#pragma unroll
  for (int o = 0; o < On; ++o) sp[SPX(tid, o)] = acc0[o];
#pragma unroll
  for (int o4 = 0; o4 < 4; ++o4) {
    float4 v = make_float4(acc0[4*o4], acc0[4*o4+1], acc0[4*o4+2], acc0[4*o4+3]);
    *(float4*)(po + 4 * o4) = v;
  }
  __syncthreads();

  // Hermite coefficients of pred_y: a = p_i, b = d0, 2c, 3d (per o).
  float* cbo = out + (size_t)Bn * Ln * On + (size_t)b * NIv * 64;
#pragma unroll 1
  for (int r = 0; r < 16; ++r) {
    const int item = r * 128 + tid;
    if (item < NIv * On) {
      const int i = item >> 4, o = item & 15;
      const float p0 = sp[SPX(i, o)], p1 = sp[SPX(i + 1, o)];
      const float rdt = frcpf(st_[i + 1] - st_[i]);
      const float si = (p1 - p0) * rdt;
      float d0;
      if (i == 0) d0 = si;
      else d0 = (p0 - sp[SPX(i - 1, o)]) * frcpf(st_[i] - st_[i - 1]);
      const float d1 = si;
      float* cc = cbo + (size_t)i * 64 + o;
      cc[0]  = p0;
      cc[16] = d0;
      cc[32] = 2.0f * (3.0f * si - 2.0f * d0 - d1) * rdt;
      cc[48] = 3.0f * (d0 + d1 - 2.0f * si) * (rdt * rdt);
    }
  }
}

extern "C" void kernel_launch(void* const* d_in, const int* in_sizes, int n_in,
                              void* d_out, int out_size, void* d_ws, size_t ws_size,
                              hipStream_t stream) {
  const float* coeffs = (const float*)d_in[0];
  const float* t      = (const float*)d_in[1];
  const float* W_init = (const float*)d_in[2];
  const float* b_init = (const float*)d_in[3];
  const float* W1     = (const float*)d_in[4];
  const float* b1     = (const float*)d_in[5];
  const float* W2     = (const float*)d_in[6];
  const float* b2     = (const float*)d_in[7];
  const float* W_read = (const float*)d_in[8];
  const float* b_read = (const float*)d_in[9];
  float* out = (float*)d_out;
  float* zt  = (float*)d_ws;   // needs B*L*H*4 = 64 MiB of scratch

  ncde_scan_kernel<<<dim3(Bn / 4), dim3(256), 0, stream>>>(
      coeffs, t, W_init, b_init, W1, b1, W2, b2, zt);
  ncde_epilogue_kernel<<<dim3(Bn), dim3(128), 0, stream>>>(
      zt, t, W_read, b_read, out);
}

// Round 3
// 1305.391 us; speedup vs baseline: 1.1424x; 1.1424x over previous
//
#include <hip/hip_runtime.h>
#include <cstdint>
#include <cstddef>

// Problem constants (fixed by the reference).
constexpr int Bn = 2048, Ln = 128, Cn = 32, Hn = 64, On = 16;
constexpr int NIv = Ln - 1;                       // 127 intervals
constexpr float K2 = 2.885390081777927f;          // 2*log2(e): tanh(x)=1-2/(1+exp2(K2*x))

typedef float v2f __attribute__((ext_vector_type(2)));

__device__ __forceinline__ float fexp2(float x) {
#if __has_builtin(__builtin_amdgcn_exp2f)
  return __builtin_amdgcn_exp2f(x);
#else
  float r; asm("v_exp_f32 %0, %1" : "=v"(r) : "v"(x)); return r;
#endif
}
__device__ __forceinline__ float frcpf(float x) {
#if __has_builtin(__builtin_amdgcn_rcpf)
  return __builtin_amdgcn_rcpf(x);
#else
  float r; asm("v_rcp_f32 %0, %1" : "=v"(r) : "v"(x)); return r;
#endif
}
__device__ __forceinline__ float tanh_fast(float x) {
  float e = fexp2(K2 * x);
  return fmaf(-2.0f, frcpf(e + 1.0f), 1.0f);
}

__device__ __forceinline__ v2f pk_fma(v2f a, v2f b, v2f c) {
  v2f d;
  asm("v_pk_fma_f32 %0, %1, %2, %3" : "=v"(d) : "v"(a), "v"(b), "v"(c));
  return d;
}

// One DPP add step of a butterfly reduce (full-rate VALU, no LDS).
template<int CTRL>
__device__ __forceinline__ float dpp_addstep(float p) {
  int q = __builtin_amdgcn_update_dpp(0, __float_as_int(p), CTRL, 0xF, 0xF, true);
  return p + __int_as_float(q);
}
// After these 4 steps every 16-lane row holds its row-sum in all lanes.
__device__ __forceinline__ float dpp_rowsum16(float p) {
  p = dpp_addstep<0xB1>(p);    // quad_perm [1,0,3,2]  (xor1)
  p = dpp_addstep<0x4E>(p);    // quad_perm [2,3,0,1]  (xor2)
  p = dpp_addstep<0x141>(p);   // row_half_mirror      (xor7 ~ xor4)
  p = dpp_addstep<0x140>(p);   // row_mirror           (xor15 ~ xor8)
  return p;
}
__device__ __forceinline__ float lane4_total(float p) {
  float s0 = __int_as_float(__builtin_amdgcn_readlane(__float_as_int(p), 0));
  float s1 = __int_as_float(__builtin_amdgcn_readlane(__float_as_int(p), 16));
  float s2 = __int_as_float(__builtin_amdgcn_readlane(__float_as_int(p), 32));
  float s3 = __int_as_float(__builtin_amdgcn_readlane(__float_as_int(p), 48));
  return (s0 + s1) + (s2 + s3);
}

// ---------------------------------------------------------------------------
// Kernel 1: the sequential RK4 scan. One wave64 per batch element; lane = h.
// W2/b2 (pre-scaled by K2) live in NAMED v2f registers (96 VGPRs) — macro
// unrolled so no array ever exists (rule #20: arrays => scratch).
// ---------------------------------------------------------------------------
#define REP8(M) M(0) M(1) M(2) M(3) M(4) M(5) M(6) M(7)

__global__ __launch_bounds__(256, 2) void ncde_scan_kernel(
    const float* __restrict__ coeffs, const float* __restrict__ t,
    const float* __restrict__ W_init, const float* __restrict__ b_init,
    const float* __restrict__ W1, const float* __restrict__ b1,
    const float* __restrict__ W2, const float* __restrict__ b2,
    float* __restrict__ zt)
{
  __shared__ float sdx[4][5][32];     // [wave][s-index][c]
  const int wv = threadIdx.x >> 6;
  const int lane = threadIdx.x & 63;
  const int b = (blockIdx.x << 2) | wv;
  float* const sdxw = &sdx[wv][0][0];

  // Per-lane weights. W1 (H,2); W2 (2, H*C); lane h owns W2[:, h*32 .. h*32+31].
  const float w10 = W1[2 * lane], w11 = W1[2 * lane + 1];
  const float sb0 = b1[0], sb1 = b1[1];

#define DECLW(g) v2f w20a##g, w20b##g, w21a##g, w21b##g, ba##g, bb##g;
  REP8(DECLW)
  {
    const float* W2a = W2 + lane * 32;
    const float* W2b = W2 + 2048 + lane * 32;
    const float* b2a = b2 + lane * 32;
#define LOADW(g) { \
      const float4 x0 = *(const float4*)(W2a + 4 * (g)); \
      const float4 x1 = *(const float4*)(W2b + 4 * (g)); \
      const float4 x2 = *(const float4*)(b2a + 4 * (g)); \
      w20a##g = (v2f){x0.x * K2, x0.y * K2}; w20b##g = (v2f){x0.z * K2, x0.w * K2}; \
      w21a##g = (v2f){x1.x * K2, x1.y * K2}; w21b##g = (v2f){x1.z * K2, x1.w * K2}; \
      ba##g   = (v2f){x2.x * K2, x2.y * K2}; bb##g   = (v2f){x2.z * K2, x2.w * K2}; }
    REP8(LOADW)
  }

  // z0 = X0 @ W_init + b_init, X0 = a-part of interval 0.
  const float* cb0 = coeffs + (size_t)b * NIv * 128;
  if (lane < 32) sdxw[lane] = cb0[lane];
  __builtin_amdgcn_wave_barrier();
  float z = b_init[lane];
#pragma unroll 4
  for (int c = 0; c < 32; ++c)
    z = fmaf(sdxw[c], W_init[(c << 6) + lane], z);
  zt[(size_t)b * Ln * Hn + lane] = tanh_fast(z);

#pragma unroll 1
  for (int i = 0; i < NIv; ++i) {
    const float* cb = cb0 + (size_t)i * 128;
    const float dti = t[i + 1] - t[i];
    const float hst = 0.5f * dti;
    // Precompute the 5 distinct dXdt vectors (s = 0, .25, .5, .75, 1 times dti).
    __builtin_amdgcn_wave_barrier();
    if (lane < 32) {
      const float bi = cb[32 + lane];
      const float ci = cb[64 + lane];
      const float di = cb[96 + lane];
      const float q = 0.25f * dti;
#pragma unroll
      for (int k = 0; k < 5; ++k) {
        const float s = q * (float)k;
        sdxw[k * 32 + lane] = fmaf(fmaf(di, s, ci), s, bi);
      }
    }
    __builtin_amdgcn_wave_barrier();

    float kacc = 0.0f, kprev = 0.0f;
#pragma unroll
    for (int j = 0; j < 2; ++j) {          // N_SUB substeps
      if (j == 1) { z = fmaf(hst * (1.0f / 6.0f), kacc, z); kacc = 0.0f; kprev = 0.0f; }
#pragma unroll
      for (int st = 0; st < 4; ++st) {     // RK4 stages
        const float cin = (st == 0) ? 0.0f : (st == 3) ? hst : 0.5f * hst;
        const float wgt = (st == 1 || st == 2) ? 2.0f : 1.0f;
        const int kidx = 2 * j + ((st + 1) >> 1);          // compile-time 0..4
        const float* dx = sdxw + kidx * 32;
        const float zs = fmaf(cin, kprev, z);
        // h1 = relu(zs @ W1 + b1): DPP butterfly, two interleaved chains.
        float p0 = dpp_rowsum16(zs * w10);
        float p1 = dpp_rowsum16(zs * w11);
        const float h10 = fmaxf(lane4_total(p0) + sb0, 0.0f);
        const float h11 = fmaxf(lane4_total(p1) + sb1, 0.0f);
        const v2f hb0 = (v2f){h10, h10};
        const v2f hb1 = (v2f){h11, h11};
        float a0 = 0.0f, a1 = 0.0f, a2 = 0.0f, a3 = 0.0f;
#define GRP(g) { \
        const float4 d4 = *(const float4*)(dx + 4 * (g)); \
        const v2f u0 = pk_fma(w20a##g, hb0, pk_fma(w21a##g, hb1, ba##g)); \
        const v2f u1 = pk_fma(w20b##g, hb0, pk_fma(w21b##g, hb1, bb##g)); \
        const float e0 = fexp2(u0.x), e1 = fexp2(u0.y); \
        const float e2 = fexp2(u1.x), e3 = fexp2(u1.y); \
        const float r0 = frcpf(e0 + 1.0f), r1 = frcpf(e1 + 1.0f); \
        const float r2 = frcpf(e2 + 1.0f), r3 = frcpf(e3 + 1.0f); \
        a0 = fmaf(fmaf(-2.0f, r0, 1.0f), d4.x, a0); \
        a1 = fmaf(fmaf(-2.0f, r1, 1.0f), d4.y, a1); \
        a2 = fmaf(fmaf(-2.0f, r2, 1.0f), d4.z, a2); \
        a3 = fmaf(fmaf(-2.0f, r3, 1.0f), d4.w, a3); }
        REP8(GRP)
        const float acc = (a0 + a1) + (a2 + a3);
        kprev = acc;
        kacc = fmaf(wgt, acc, kacc);
      }
    }
    z = fmaf(hst * (1.0f / 6.0f), kacc, z);
    zt[((size_t)b * Ln + (i + 1)) * Hn + lane] = tanh_fast(z);
  }
}

// ---------------------------------------------------------------------------
// Kernel 2: readout + hermite coeffs. One block per batch element.
// ---------------------------------------------------------------------------
#define SPX(l_, o_) (((l_) << 4) | (((o_) + (l_)) & 15))
#define SZX(l_, h_) (((l_) << 6) | (((h_) + (l_)) & 63))

__global__ __launch_bounds__(128, 2) void ncde_epilogue_kernel(
    const float* __restrict__ zt, const float* __restrict__ t,
    const float* __restrict__ W_read, const float* __restrict__ b_read,
    float* __restrict__ out)
{
  __shared__ float sW[Hn * On];
  __shared__ float sz[Ln * Hn];
  __shared__ float sp[Ln * On];
  __shared__ float st_[Ln];
  const int b = blockIdx.x;
  const int tid = threadIdx.x;

  for (int i2 = tid; i2 < Hn * On; i2 += 128) sW[i2] = W_read[i2];
  st_[tid] = t[tid];
  const float* zb = zt + (size_t)b * Ln * Hn;
#pragma unroll 1
  for (int r = 0; r < 16; ++r) {
    const int base = (r * 128 + tid) * 4;       // 8192 floats, float4-granular
    const float4 v = *(const float4*)(zb + base);
    const int l = base >> 6, h = base & 63;     // h multiple of 4, no row wrap
    sz[SZX(l, h + 0)] = v.x;
    sz[SZX(l, h + 1)] = v.y;
    sz[SZX(l, h + 2)] = v.z;
    sz[SZX(l, h + 3)] = v.w;
  }
  __syncthreads();

  // Readout: thread tid owns row l = tid, all 16 outputs in registers.
  float acc0[On];
#pragma unroll
  for (int o = 0; o < On; ++o) acc0[o] = b_read[o];
#pragma unroll 2
  for (int h = 0; h < Hn; ++h) {
    const float zv = sz[SZX(tid, h)];
#pragma unroll
    for (int o = 0; o < On; ++o) acc0[o] = fmaf(zv, sW[h * On + o], acc0[o]);
  }
  float* po = out + ((size_t)b * Ln + tid) * On;
#pragma unroll
  for (int o = 0; o < On; ++o) sp[SPX(tid, o)] = acc0[o];
#pragma unroll
  for (int o4 = 0; o4 < 4; ++o4) {
    float4 v = make_float4(acc0[4*o4], acc0[4*o4+1], acc0[4*o4+2], acc0[4*o4+3]);
    *(float4*)(po + 4 * o4) = v;
  }
  __syncthreads();

  // Hermite coefficients of pred_y: a = p_i, b = d0, 2c, 3d (per o).
  float* cbo = out + (size_t)Bn * Ln * On + (size_t)b * NIv * 64;
#pragma unroll 1
  for (int r = 0; r < 16; ++r) {
    const int item = r * 128 + tid;
    if (item < NIv * On) {
      const int i = item >> 4, o = item & 15;
      const float p0 = sp[SPX(i, o)], p1 = sp[SPX(i + 1, o)];
      const float rdt = frcpf(st_[i + 1] - st_[i]);
      const float si = (p1 - p0) * rdt;
      float d0;
      if (i == 0) d0 = si;
      else d0 = (p0 - sp[SPX(i - 1, o)]) * frcpf(st_[i] - st_[i - 1]);
      const float d1 = si;
      float* cc = cbo + (size_t)i * 64 + o;
      cc[0]  = p0;
      cc[16] = d0;
      cc[32] = 2.0f * (3.0f * si - 2.0f * d0 - d1) * rdt;
      cc[48] = 3.0f * (d0 + d1 - 2.0f * si) * (rdt * rdt);
    }
  }
}

extern "C" void kernel_launch(void* const* d_in, const int* in_sizes, int n_in,
                              void* d_out, int out_size, void* d_ws, size_t ws_size,
                              hipStream_t stream) {
  const float* coeffs = (const float*)d_in[0];
  const float* t      = (const float*)d_in[1];
  const float* W_init = (const float*)d_in[2];
  const float* b_init = (const float*)d_in[3];
  const float* W1     = (const float*)d_in[4];
  const float* b1     = (const float*)d_in[5];
  const float* W2     = (const float*)d_in[6];
  const float* b2     = (const float*)d_in[7];
  const float* W_read = (const float*)d_in[8];
  const float* b_read = (const float*)d_in[9];
  float* out = (float*)d_out;
  float* zt  = (float*)d_ws;   // needs B*L*H*4 = 64 MiB of scratch

  ncde_scan_kernel<<<dim3(Bn / 4), dim3(256), 0, stream>>>(
      coeffs, t, W_init, b_init, W1, b1, W2, b2, zt);
  ncde_epilogue_kernel<<<dim3(Bn), dim3(128), 0, stream>>>(
      zt, t, W_read, b_read, out);
}